// Round 6
// baseline (724.182 us; speedup 1.0000x reference)
//
#include <hip/hip_runtime.h>

// RNNDecoderP round 13: MEGA-WAVE. One 64-lane wave owns one (b,kb) chain:
// L1 recurrence + gx2 + L2 recurrence + MLP head + y, interleaved at 1-step
// lag so each layer's LDS gather latency hides under the other layer's
// compute. No __syncthreads, no rings, no pipeline skew, no co-wave fights.
// Weight arrays (160 VGPRs) are pinned resident via "+v" asm redefinition
// (unrematerializable) -- the r10/r11/r12 regressions were all the allocator
// spilling weights back into the loop. __launch_bounds__(64,1) +
// waves_per_eu(1,1) gives the 512-VGPR budget.
// Math is op-for-op identical to round 8 (absmax must match).

typedef float v2f __attribute__((ext_vector_type(2)));

constexpr int Bn  = 256;
constexpr int Tn  = 2048;
constexpr int Dn  = 64;
constexpr int DBn = 32;
constexpr int Ln  = 2;
constexpr int Gn  = 96;

#if __has_builtin(__builtin_amdgcn_exp2f)
__device__ __forceinline__ float exp2_fast(float x) { return __builtin_amdgcn_exp2f(x); }
#else
__device__ __forceinline__ float exp2_fast(float x) { return exp2f(x); }
#endif
#if __has_builtin(__builtin_amdgcn_rcpf)
__device__ __forceinline__ float rcp_fast(float x) { return __builtin_amdgcn_rcpf(x); }
#else
__device__ __forceinline__ float rcp_fast(float x) { return 1.0f / x; }
#endif

__device__ __forceinline__ float sigmoid_f(float x) {
  return rcp_fast(1.0f + exp2_fast(-1.4426950408889634f * x));
}
__device__ __forceinline__ float tanh_f(float x) {
  return 1.0f - 2.0f * rcp_fast(1.0f + exp2_fast(2.8853900817779268f * x));
}

template <int CTRL>
__device__ __forceinline__ float dpp_add(float x) {
  int y = __builtin_amdgcn_update_dpp(0, __builtin_bit_cast(int, x), CTRL, 0xf, 0xf, true);
  return x + __builtin_bit_cast(float, y);
}
// cross-half (L^8) combine: row_ror:8
__device__ __forceinline__ float dppx8_add(float x) { return dpp_add<0x128>(x); }
// full 16-lane row sum, result in ALL lanes: ror8+ror4+ror2+ror1 circulant reduce
__device__ __forceinline__ float dpp_row_sum16(float x) {
  x = dpp_add<0x128>(x);
  x = dpp_add<0x124>(x);
  x = dpp_add<0x122>(x);
  x = dpp_add<0x121>(x);
  return x;
}

// 16-float half-dot, single chain (off-chain work)
__device__ __forceinline__ float dot8(const v2f* __restrict__ w, const v2f* __restrict__ h) {
  v2f a = {0.0f, 0.0f};
  #pragma unroll
  for (int q = 0; q < 8; ++q) a = __builtin_elementwise_fma(w[q], h[q], a);
  return a.x + a.y;
}
// 16-float half-dot, two chains (on-chain work)
__device__ __forceinline__ float dot8b(const v2f* __restrict__ w, const v2f* __restrict__ h) {
  v2f a = {0.0f, 0.0f}, b = {0.0f, 0.0f};
  #pragma unroll
  for (int q = 0; q < 4; ++q) {
    a = __builtin_elementwise_fma(w[q], h[q], a);
    b = __builtin_elementwise_fma(w[q + 4], h[q + 4], b);
  }
  a = a + b;
  return a.x + a.y;
}

// load 16 consecutive floats (4 x float4) into v2f[8]
__device__ __forceinline__ void ld16(const float* p, v2f* d) {
  #pragma unroll
  for (int q = 0; q < 4; ++q) {
    float4 a = ((const float4*)p)[q];
    d[2*q] = (v2f){a.x, a.y}; d[2*q+1] = (v2f){a.z, a.w};
  }
}

// Anti-remat pin: redefine each element through empty asm. An asm-defined
// value cannot be rematerialized from its originating load, so the array
// must stay register-resident (budget 512 VGPR at 1 wave/EU).
__device__ __forceinline__ void pin8(v2f* a) {
  #pragma unroll
  for (int q = 0; q < 8; ++q) {
    float x = a[q].x, y = a[q].y;
    asm volatile("" : "+v"(x), "+v"(y));
    a[q].x = x; a[q].y = y;
  }
}

__global__ __launch_bounds__(64, 1)
__attribute__((amdgpu_waves_per_eu(1, 1)))
void rnn_decoder(const int* __restrict__ band_ids, const float* __restrict__ dtime,
                 const float* __restrict__ z_last, const float* __restrict__ projW,
                 const float* __restrict__ projB, const float* __restrict__ Wih,
                 const float* __restrict__ Whh, const float* __restrict__ bih,
                 const float* __restrict__ bhh, const float* __restrict__ mW1,
                 const float* __restrict__ mb1, const float* __restrict__ mW2,
                 const float* __restrict__ mb2, float* __restrict__ out) {
  const int b    = blockIdx.x >> 1;
  const int kb   = blockIdx.x & 1;
  const int L    = threadIdx.x;              // 0..63, single wave
  const int e    = (L & 7) | ((L >> 4) << 3);// owned element/gate 0..31
  const int koff = ((L >> 3) & 1) * 16;      // K-half (bit 3 -> DPP partner L^8)

  __shared__ __align__(16) float yd[Tn];       // compacted dtime -> y
  __shared__ __align__(16) float vr[32][4];    // y-partials (4 row sums / step)
  __shared__ __align__(16) float h1b[DBn];     // h1 self-gather buffer
  __shared__ __align__(16) float h2b[DBn];     // h2 self-gather buffer
  __shared__ __align__(16) float xb[DBn], xs[DBn];

  // ======== compaction: stable-compact this band's dtime to yd[0..n) ========
  int n0;
  {
    const int*   brow = band_ids + b * Tn;
    const float* drow = dtime    + b * Tn;
    int cnt = 0;
    int4 bcache[8];
    #pragma unroll
    for (int it = 0; it < 8; ++it) {
      int4 v = ((const int4*)(brow + L * 32))[it];
      bcache[it] = v;
      cnt += (v.x == kb) + (v.y == kb) + (v.z == kb) + (v.w == kb);
    }
    int incl = cnt;
    #pragma unroll
    for (int dlt = 1; dlt < 64; dlt <<= 1) {
      int v = __shfl_up(incl, dlt, 64);
      if (L >= dlt) incl += v;
    }
    int off = incl - cnt;
    n0 = __shfl(incl, 63, 64);
    #pragma unroll
    for (int it = 0; it < 8; ++it) {
      int4   v  = bcache[it];
      float4 dd = ((const float4*)(drow + L * 32))[it];
      if (v.x == kb) yd[off++] = dd.x;
      if (v.y == kb) yd[off++] = dd.y;
      if (v.z == kb) yd[off++] = dd.z;
      if (v.w == kb) yd[off++] = dd.w;
    }
  }
  const int n = __builtin_amdgcn_readfirstlane(n0);

  // ======== proj fold: x(t) = xb + d(t)*xs ========
  {
    const float* pw = projW + (kb * (Dn + 1)) * DBn + e;
    const float* zl = z_last + b * Dn;
    float acc = 0.0f;
    #pragma unroll 8
    for (int k = 0; k < Dn; ++k) acc = fmaf(zl[k], pw[k * DBn], acc);
    xb[e] = acc + projB[kb * DBn + e];   // partner lanes write identical values
    xs[e] = pw[Dn * DBn];
  }
  __builtin_amdgcn_wave_barrier();

  // ======== L1 gate affine consts: g = gb + d*gs ========
  const float* wih1  = Wih + ((kb * Ln + 0) * Gn) * DBn;
  const float* bih1p = bih + (kb * Ln + 0) * Gn;
  const float* bhh1p = bhh + (kb * Ln + 0) * Gn;
  float gb_r = 0, gb_z = 0, gb_n = 0, gs_r = 0, gs_z = 0, gs_n = 0;
  #pragma unroll 4
  for (int j = 0; j < DBn; ++j) {
    float xbv = xb[j], xsv = xs[j];
    float wr = wih1[(     e) * DBn + j];
    float wz = wih1[(32 + e) * DBn + j];
    float wn = wih1[(64 + e) * DBn + j];
    gb_r = fmaf(wr, xbv, gb_r);  gs_r = fmaf(wr, xsv, gs_r);
    gb_z = fmaf(wz, xbv, gb_z);  gs_z = fmaf(wz, xsv, gs_z);
    gb_n = fmaf(wn, xbv, gb_n);  gs_n = fmaf(wn, xsv, gs_n);
  }
  gb_r += bih1p[e]      + bhh1p[e];
  gb_z += bih1p[32 + e] + bhh1p[32 + e];
  gb_n += bih1p[64 + e];
  float bhh1n = bhh1p[64 + e];

  // ======== resident weights (pinned) ========
  v2f w1r[8], w1z[8], w1n[8];                  // Whh1 half-rows
  const float* whh1 = Whh + ((kb * Ln + 0) * Gn) * DBn;
  ld16(whh1 + (     e) * DBn + koff, w1r);
  ld16(whh1 + (32 + e) * DBn + koff, w1z);
  ld16(whh1 + (64 + e) * DBn + koff, w1n);
  v2f wa[8], wbv[8], wcv[8];                   // Wih2 half-rows (gx2)
  const float* wih2 = Wih + ((kb * Ln + 1) * Gn) * DBn;
  ld16(wih2 + (     e) * DBn + koff, wa);
  ld16(wih2 + (32 + e) * DBn + koff, wbv);
  ld16(wih2 + (64 + e) * DBn + koff, wcv);
  v2f r2w[8], z2w[8], n2w[8];                  // Whh2 half-rows
  const float* whh2  = Whh + ((kb * Ln + 1) * Gn) * DBn;
  ld16(whh2 + (     e) * DBn + koff, r2w);
  ld16(whh2 + (32 + e) * DBn + koff, z2w);
  ld16(whh2 + (64 + e) * DBn + koff, n2w);
  v2f m1c[8];                                  // mW1 half-column
  #pragma unroll
  for (int q = 0; q < 8; ++q)
    m1c[q] = (v2f){ mW1[(kb * DBn + koff + 2*q)     * DBn + e],
                    mW1[(kb * DBn + koff + 2*q + 1) * DBn + e] };
  const float* bih2p = bih + (kb * Ln + 1) * Gn;
  const float* bhh2p = bhh + (kb * Ln + 1) * Gn;
  float c2r   = bih2p[e]      + bhh2p[e];
  float c2z   = bih2p[32 + e] + bhh2p[32 + e];
  float bih2n = bih2p[64 + e];
  float bhh2n = bhh2p[64 + e];
  float mb1e  = mb1[kb * DBn + e];
  float mW2h  = 0.5f * mW2[kb * DBn + e];      // pre-scaled for dual-count
  float mb2v  = mb2[kb];

  pin8(w1r); pin8(w1z); pin8(w1n);
  pin8(wa);  pin8(wbv); pin8(wcv);
  pin8(r2w); pin8(z2w); pin8(n2w);
  pin8(m1c);
  asm volatile("" : "+v"(gb_r), "+v"(gb_z), "+v"(gb_n),
                    "+v"(gs_r), "+v"(gs_z), "+v"(gs_n),
                    "+v"(bhh1n), "+v"(c2r), "+v"(c2z), "+v"(bih2n),
                    "+v"(bhh2n), "+v"(mb1e), "+v"(mW2h), "+v"(mb2v));

  // ======== interleaved recurrence loop ========
  // iter t: L1 step t (h1a=h1(t-1)); gx2(t-1) from same h1a; L2 step t-1
  // (h2a=h2(t-2)); MLP/y step t-2 from same h2a. LDS gather of each layer
  // hides under the other layer's compute.
  v2f h1a[8], h2a[8];
  #pragma unroll
  for (int q = 0; q < 8; ++q) { h1a[q] = (v2f){0.f, 0.f}; h2a[q] = (v2f){0.f, 0.f}; }
  float h1self = 0.0f, h2self = 0.0f;
  __builtin_amdgcn_wave_barrier();
  float dcur = yd[0];                          // garbage iff n==0 (unused then)

  for (int t = 0; t < n + 2; ++t) {
    const bool do1 = t < n;
    const bool do2 = (t >= 1) && (t <= n);
    const bool doy = t >= 2;

    float ar, az, an;
    if (do1) {                                 // L1 dots on h1(t-1)
      ar = dot8b(w1r, h1a);
      az = dot8b(w1z, h1a);
      an = dot8b(w1n, h1a);
    }
    float g0, g1, g2;
    if (do2) {                                 // gx2(t-1) -- h1a still h1(t-1)
      g0 = dppx8_add(dot8(wa,  h1a));
      g1 = dppx8_add(dot8(wbv, h1a));
      g2 = dppx8_add(dot8(wcv, h1a));
    }
    if (do1) {                                 // L1 gates -> h1(t), write+gather
      ar = dppx8_add(ar);
      az = dppx8_add(az);
      an = dppx8_add(an);
      float r1 = sigmoid_f(fmaf(dcur, gs_r, gb_r) + ar);
      float z1 = sigmoid_f(fmaf(dcur, gs_z, gb_z) + az);
      float n1 = tanh_f(fmaf(dcur, gs_n, gb_n) + r1 * (an + bhh1n));
      h1self = fmaf(z1, h1self - n1, n1);
      h1b[e] = h1self;
      __builtin_amdgcn_wave_barrier();
      ld16(&h1b[koff], h1a);                   // latency hides under L2/MLP below
    }
    float cr, cz, cn;
    if (do2) {                                 // L2 dots on h2(t-2)
      cr = dot8b(r2w, h2a);
      cz = dot8b(z2w, h2a);
      cn = dot8b(n2w, h2a);
    }
    float vpart;
    if (doy) {                                 // MLP on h2(t-2) -- before overwrite
      float mh = dppx8_add(dot8(m1c, h2a));
      vpart = dpp_row_sum16(fmaxf(mh + mb1e, 0.0f) * mW2h);
    }
    if (do2) {                                 // L2 gates -> h2(t-1), write+gather
      cr = dppx8_add(cr);
      cz = dppx8_add(cz);
      cn = dppx8_add(cn);
      float r2v = sigmoid_f(g0 + cr + c2r);
      float z2v = sigmoid_f(g1 + cz + c2z);
      float n2v = tanh_f(g2 + bih2n + r2v * (cn + bhh2n));
      h2self = fmaf(z2v, h2self - n2v, n2v);
      h2b[e] = h2self;
      __builtin_amdgcn_wave_barrier();
      ld16(&h2b[koff], h2a);                   // latency hides under next L1
    }
    if (doy) {                                 // y(t-2) partials + batched drain
      const int s = (t - 2) & 31;
      if ((L & 15) == 15) vr[s][L >> 4] = vpart;
      if (s == 31) {
        __builtin_amdgcn_wave_barrier();
        if (L < 32) {
          float4 p = *(const float4*)&vr[L][0];
          yd[t - 33 + L] = ((p.x + p.y) + (p.z + p.w)) + mb2v;
        }
      }
    }
    const int tnx = (t + 1 < n) ? (t + 1) : 0; // prefetch d for next iter
    dcur = yd[tnx];
  }

  // ======== epilogue: final drain, tail fill, store ========
  float ylast;
  if (n > 0) {
    const int sl = (n - 1) & 31;
    if (sl != 31) {                            // slots 0..sl not yet drained
      __builtin_amdgcn_wave_barrier();
      if (L <= sl) {
        float4 p = *(const float4*)&vr[L][0];
        yd[(n - 1) - sl + L] = ((p.x + p.y) + (p.z + p.w)) + mb2v;
      }
    }
    __builtin_amdgcn_wave_barrier();
    ylast = yd[n - 1];
  } else {
    float p0 = dpp_row_sum16(fmaxf(mb1e, 0.0f) * mW2h);
    if ((L & 15) == 15) vr[0][L >> 4] = p0;
    __builtin_amdgcn_wave_barrier();
    float4 p = *(const float4*)&vr[0][0];
    ylast = ((p.x + p.y) + (p.z + p.w)) + mb2v;
  }
  for (int t = n + L; t < Tn; t += 64) yd[t] = ylast;
  __builtin_amdgcn_wave_barrier();

  float* orow = out + (kb * Bn + b) * Tn;
  #pragma unroll 2
  for (int q = L; q < Tn / 4; q += 64)
    ((float4*)orow)[q] = ((const float4*)yd)[q];
}

extern "C" void kernel_launch(void* const* d_in, const int* in_sizes, int n_in,
                              void* d_out, int out_size, void* d_ws, size_t ws_size,
                              hipStream_t stream) {
  const int*   band_ids = (const int*)  d_in[0];
  const float* dtime    = (const float*)d_in[1];
  const float* z_last   = (const float*)d_in[2];
  const float* projW    = (const float*)d_in[3];
  const float* projB    = (const float*)d_in[4];
  const float* Wih      = (const float*)d_in[5];
  const float* Whh      = (const float*)d_in[6];
  const float* bihp     = (const float*)d_in[7];
  const float* bhhp     = (const float*)d_in[8];
  const float* mW1      = (const float*)d_in[9];
  const float* mb1      = (const float*)d_in[10];
  const float* mW2      = (const float*)d_in[11];
  const float* mb2      = (const float*)d_in[12];
  float* out = (float*)d_out;
  rnn_decoder<<<dim3(Bn * 2), dim3(64), 0, stream>>>(
      band_ids, dtime, z_last, projW, projB, Wih, Whh, bihp, bhhp,
      mW1, mb1, mW2, mb2, out);
}

// Round 7
// 368.845 us; speedup vs baseline: 1.9634x; 1.9634x over previous
//
#include <hip/hip_runtime.h>

// RNNDecoderP round 14: deterministic SIMD pairing via one 8-wave block/CU.
// Grid 256 (one block per batch row, both bands). Waves -> SIMD wv%4:
//   SIMD0: wv0 L1(b0) + wv4 MLP+drain(b1)
//   SIMD1: wv1 L1(b1) + wv5 MLP+drain(b0)
//   SIMD2: wv2 L2+gx2(b0) + wv6 setup/idle
//   SIMD3: wv3 L2+gx2(b1) + wv7 setup/idle
// Each recurrence chain shares its SIMD with a light helper instead of a
// second full chain (round-8's hidden cost). gx2 folded into the L2 wave
// OFF-chain (h1 input is a chunk old) -> gxr ring gone, skew C+4 -> C+3.
// Kc=32 and all inner math verbatim from round 8 (the only VGPR-stable
// config; launch_bounds(512,2) caps at 256 VGPR/wave -- never collapsed).
// 32KB LDS pad forces exactly 1 block/CU.

typedef float v2f __attribute__((ext_vector_type(2)));

constexpr int Bn  = 256;
constexpr int Tn  = 2048;
constexpr int Dn  = 64;
constexpr int DBn = 32;
constexpr int Ln  = 2;
constexpr int Gn  = 96;
constexpr int Kc  = 32;     // steps per chunk/phase

#if __has_builtin(__builtin_amdgcn_exp2f)
__device__ __forceinline__ float exp2_fast(float x) { return __builtin_amdgcn_exp2f(x); }
#else
__device__ __forceinline__ float exp2_fast(float x) { return exp2f(x); }
#endif
#if __has_builtin(__builtin_amdgcn_rcpf)
__device__ __forceinline__ float rcp_fast(float x) { return __builtin_amdgcn_rcpf(x); }
#else
__device__ __forceinline__ float rcp_fast(float x) { return 1.0f / x; }
#endif

__device__ __forceinline__ float sigmoid_f(float x) {
  return rcp_fast(1.0f + exp2_fast(-1.4426950408889634f * x));
}
__device__ __forceinline__ float tanh_f(float x) {
  return 1.0f - 2.0f * rcp_fast(1.0f + exp2_fast(2.8853900817779268f * x));
}

template <int CTRL>
__device__ __forceinline__ float dpp_add(float x) {
  int y = __builtin_amdgcn_update_dpp(0, __builtin_bit_cast(int, x), CTRL, 0xf, 0xf, true);
  return x + __builtin_bit_cast(float, y);
}
// cross-half (L^8) combine: row_ror:8
__device__ __forceinline__ float dppx8_add(float x) { return dpp_add<0x128>(x); }
// full 16-lane row sum, result in ALL lanes: ror8+ror4+ror2+ror1 circulant reduce
__device__ __forceinline__ float dpp_row_sum16(float x) {
  x = dpp_add<0x128>(x);
  x = dpp_add<0x124>(x);
  x = dpp_add<0x122>(x);
  x = dpp_add<0x121>(x);
  return x;
}

// 16-float half-dot, single chain (off-chain work)
__device__ __forceinline__ float dot8(const v2f* __restrict__ w, const v2f* __restrict__ h) {
  v2f a = {0.0f, 0.0f};
  #pragma unroll
  for (int q = 0; q < 8; ++q) a = __builtin_elementwise_fma(w[q], h[q], a);
  return a.x + a.y;
}
// 16-float half-dot, two chains (on-chain work)
__device__ __forceinline__ float dot8b(const v2f* __restrict__ w, const v2f* __restrict__ h) {
  v2f a = {0.0f, 0.0f}, b = {0.0f, 0.0f};
  #pragma unroll
  for (int q = 0; q < 4; ++q) {
    a = __builtin_elementwise_fma(w[q], h[q], a);
    b = __builtin_elementwise_fma(w[q + 4], h[q + 4], b);
  }
  a = a + b;
  return a.x + a.y;
}

// load 16 consecutive floats (4 x float4) into v2f[8]
__device__ __forceinline__ void ld16(const float* p, v2f* d) {
  #pragma unroll
  for (int q = 0; q < 4; ++q) {
    float4 a = ((const float4*)p)[q];
    d[2*q] = (v2f){a.x, a.y}; d[2*q+1] = (v2f){a.z, a.w};
  }
}

__global__ __launch_bounds__(512, 2)
void rnn_decoder(const int* __restrict__ band_ids, const float* __restrict__ dtime,
                 const float* __restrict__ z_last, const float* __restrict__ projW,
                 const float* __restrict__ projB, const float* __restrict__ Wih,
                 const float* __restrict__ Whh, const float* __restrict__ bih,
                 const float* __restrict__ bhh, const float* __restrict__ mW1,
                 const float* __restrict__ mb1, const float* __restrict__ mW2,
                 const float* __restrict__ mb2, float* __restrict__ out) {
  const int b    = blockIdx.x;               // batch row; block owns both bands
  const int tid  = threadIdx.x;              // 0..511
  const int wv   = tid >> 6;                 // physical wave -> SIMD wv&3
  const int L    = tid & 63;
  const int e    = (L & 7) | ((L >> 4) << 3);// owned element/gate 0..31
  const int koff = ((L >> 3) & 1) * 16;      // K-half (bit 3 -> DPP partner L^8)

  // role/band: wv0,1=L1(b0,b1)  wv2,3=L2+gx2(b0,b1)  wv4,5=MLP(b1,b0)  wv6,7=setup
  int role, bn;
  if (wv < 2)      { role = 0; bn = wv; }
  else if (wv < 4) { role = 1; bn = wv - 2; }
  else if (wv < 6) { role = 2; bn = 5 - wv; }
  else             { role = 3; bn = wv - 6; }
  const int kb = bn;

  __shared__ __align__(16) float yd[2][Tn];               // per-band dtime -> y (16K)
  __shared__ __align__(16) float h1r[2][2][Kc][DBn];      // L1 -> L2 rings (16K)
  __shared__ __align__(16) float h2r[2][2][Kc][DBn];      // L2 -> MLP rings (16K)
  __shared__ __align__(16) float vr[2][2][Kc][4];         // MLP -> drain partials (2K)
  __shared__ __align__(16) float xb[2][DBn], xs[2][DBn];
  __shared__ int nsh[2];
  __shared__ float ldspad[8192];                          // +32K: force 1 block/CU
  if (tid == 0) ((volatile float*)ldspad)[0] = 0.0f;

  // ======================= setup (per role) =======================
  if (role == 3) {
    // compaction for band bn: stable-compact dtime where band_ids==bn
    const int*   brow = band_ids + b * Tn;
    const float* drow = dtime    + b * Tn;
    int cnt = 0;
    int4 bcache[8];
    #pragma unroll
    for (int it = 0; it < 8; ++it) {
      int4 v = ((const int4*)(brow + L * 32))[it];
      bcache[it] = v;
      cnt += (v.x == kb) + (v.y == kb) + (v.z == kb) + (v.w == kb);
    }
    int incl = cnt;
    #pragma unroll
    for (int dlt = 1; dlt < 64; dlt <<= 1) {
      int v = __shfl_up(incl, dlt, 64);
      if (L >= dlt) incl += v;
    }
    int off = incl - cnt;
    const int nb0 = __shfl(incl, 63, 64);
    #pragma unroll
    for (int it = 0; it < 8; ++it) {
      int4   v  = bcache[it];
      float4 dd = ((const float4*)(drow + L * 32))[it];
      if (v.x == kb) yd[bn][off++] = dd.x;
      if (v.y == kb) yd[bn][off++] = dd.y;
      if (v.z == kb) yd[bn][off++] = dd.z;
      if (v.w == kb) yd[bn][off++] = dd.w;
    }
    if (L == 0) nsh[bn] = nb0;
    __syncthreads();   // barrier A
    const int CM = (((nsh[0] + Kc - 1) >> 5) > ((nsh[1] + Kc - 1) >> 5))
                     ? ((nsh[0] + Kc - 1) >> 5) : ((nsh[1] + Kc - 1) >> 5);
    for (int c = 0; c < CM + 3; ++c) __syncthreads();   // idle companion
  } else if (role == 0) {
    // ---- L1 recurrence wave: proj fold + gate affine consts + Whh1 ----
    {
      const float* pw = projW + (kb * (Dn + 1)) * DBn + e;
      const float* zl = z_last + b * Dn;
      float acc = 0.0f;
      #pragma unroll 8
      for (int k = 0; k < Dn; ++k) acc = fmaf(zl[k], pw[k * DBn], acc);
      xb[bn][e] = acc + projB[kb * DBn + e];   // partner lanes write same value
      xs[bn][e] = pw[Dn * DBn];
    }
    __builtin_amdgcn_wave_barrier();
    const float* wih1  = Wih + ((kb * Ln + 0) * Gn) * DBn;
    const float* bih1p = bih + (kb * Ln + 0) * Gn;
    const float* bhh1p = bhh + (kb * Ln + 0) * Gn;
    float gb_r = 0, gb_z = 0, gb_n = 0, gs_r = 0, gs_z = 0, gs_n = 0;
    #pragma unroll 4
    for (int j = 0; j < DBn; ++j) {
      float xbv = xb[bn][j], xsv = xs[bn][j];
      float wr = wih1[(     e) * DBn + j];
      float wz = wih1[(32 + e) * DBn + j];
      float wn = wih1[(64 + e) * DBn + j];
      gb_r = fmaf(wr, xbv, gb_r);  gs_r = fmaf(wr, xsv, gs_r);
      gb_z = fmaf(wz, xbv, gb_z);  gs_z = fmaf(wz, xsv, gs_z);
      gb_n = fmaf(wn, xbv, gb_n);  gs_n = fmaf(wn, xsv, gs_n);
    }
    gb_r += bih1p[e]      + bhh1p[e];
    gb_z += bih1p[32 + e] + bhh1p[32 + e];
    gb_n += bih1p[64 + e];
    const float bhh1n = bhh1p[64 + e];
    v2f w1r[8], w1z[8], w1n[8];
    const float* whh1 = Whh + ((kb * Ln + 0) * Gn) * DBn;
    ld16(whh1 + (     e) * DBn + koff, w1r);
    ld16(whh1 + (32 + e) * DBn + koff, w1z);
    ld16(whh1 + (64 + e) * DBn + koff, w1n);
    __syncthreads();   // barrier A

#if __has_builtin(__builtin_amdgcn_s_setprio)
    __builtin_amdgcn_s_setprio(1);
#endif
    const int C0 = (nsh[0] + Kc - 1) >> 5, C1 = (nsh[1] + Kc - 1) >> 5;
    const int CM = C0 > C1 ? C0 : C1;
    const int Cb = bn ? C1 : C0;
    const float* ydb = &yd[bn][0];
    v2f h1a[8];
    #pragma unroll
    for (int q = 0; q < 8; ++q) h1a[q] = (v2f){0.0f, 0.0f};
    float h1self = 0.0f;
    for (int c = 0; c < CM + 3; ++c) {
      if (c < Cb) {
        float* ring = &h1r[bn][c & 1][0][0];
        const int t0 = c * Kc;
        for (int k = 0; k < Kc; ++k) {
          float d  = ydb[t0 + k];
          float ar = dot8b(w1r, h1a);
          float az = dot8b(w1z, h1a);
          float an = dot8b(w1n, h1a);
          ar = dppx8_add(ar);
          az = dppx8_add(az);
          an = dppx8_add(an);
          float r1 = sigmoid_f(fmaf(d, gs_r, gb_r) + ar);
          float z1 = sigmoid_f(fmaf(d, gs_z, gb_z) + az);
          float n1 = tanh_f(fmaf(d, gs_n, gb_n) + r1 * (an + bhh1n));
          h1self = fmaf(z1, h1self - n1, n1);
          ring[k * DBn + e] = h1self;
          __builtin_amdgcn_wave_barrier();
          ld16(&ring[k * DBn + koff], h1a);   // the only dependent DS stage
        }
      }
      __syncthreads();
    }
  } else if (role == 1) {
    // ---- L2 recurrence wave with folded gx2 (off-chain; h1 a chunk old) ----
    const float* wih2 = Wih + ((kb * Ln + 1) * Gn) * DBn;
    v2f wa[8], wbv[8], wcv[8];
    ld16(wih2 + (     e) * DBn + koff, wa);
    ld16(wih2 + (32 + e) * DBn + koff, wbv);
    ld16(wih2 + (64 + e) * DBn + koff, wcv);
    const float* whh2  = Whh + ((kb * Ln + 1) * Gn) * DBn;
    const float* bih2p = bih + (kb * Ln + 1) * Gn;
    const float* bhh2p = bhh + (kb * Ln + 1) * Gn;
    v2f r2w[8], z2w[8], n2w[8];
    ld16(whh2 + (     e) * DBn + koff, r2w);
    ld16(whh2 + (32 + e) * DBn + koff, z2w);
    ld16(whh2 + (64 + e) * DBn + koff, n2w);
    const float c2r   = bih2p[e]      + bhh2p[e];
    const float c2z   = bih2p[32 + e] + bhh2p[32 + e];
    const float bih2n = bih2p[64 + e];
    const float bhh2n = bhh2p[64 + e];
    __syncthreads();   // barrier A

#if __has_builtin(__builtin_amdgcn_s_setprio)
    __builtin_amdgcn_s_setprio(1);
#endif
    const int C0 = (nsh[0] + Kc - 1) >> 5, C1 = (nsh[1] + Kc - 1) >> 5;
    const int CM = C0 > C1 ? C0 : C1;
    const int Cb = bn ? C1 : C0;
    v2f h2a[8];
    #pragma unroll
    for (int q = 0; q < 8; ++q) h2a[q] = (v2f){0.0f, 0.0f};
    float h2self = 0.0f;
    for (int c = 0; c < CM + 3; ++c) {
      if (c >= 1 && c - 1 < Cb) {
        const int cc = c - 1;
        const float* hsrc = &h1r[bn][cc & 1][0][0];
        float* ring = &h2r[bn][cc & 1][0][0];
        for (int k = 0; k < Kc; ++k) {
          v2f hb[8];
          ld16(&hsrc[k * DBn + koff], hb);     // pre-produced; off-chain
          float g0 = dppx8_add(dot8(wa,  hb)); // gx2: off-chain fill work
          float g1 = dppx8_add(dot8(wbv, hb));
          float g2 = dppx8_add(dot8(wcv, hb));
          float cr = dot8b(r2w, h2a);
          float cz = dot8b(z2w, h2a);
          float cn = dot8b(n2w, h2a);
          cr = dppx8_add(cr);
          cz = dppx8_add(cz);
          cn = dppx8_add(cn);
          float r2v = sigmoid_f(g0 + cr + c2r);
          float z2v = sigmoid_f(g1 + cz + c2z);
          float n2v = tanh_f(g2 + bih2n + r2v * (cn + bhh2n));
          h2self = fmaf(z2v, h2self - n2v, n2v);
          ring[k * DBn + e] = h2self;
          __builtin_amdgcn_wave_barrier();
          ld16(&ring[k * DBn + koff], h2a);    // chain ends here
        }
      }
      __syncthreads();
    }
  } else {
    // ---- MLP head + y-drain wave ----
    v2f m1c[8];
    #pragma unroll
    for (int q = 0; q < 8; ++q)
      m1c[q] = (v2f){ mW1[(kb * DBn + koff + 2*q)     * DBn + e],
                      mW1[(kb * DBn + koff + 2*q + 1) * DBn + e] };
    const float mb1e = mb1[kb * DBn + e];
    const float mW2h = 0.5f * mW2[kb * DBn + e];
    const float mb2v = mb2[kb];
    // n==0 fallback partials (only consumed when C==0)
    {
      float p = fmaxf(mb1e, 0.0f) * mW2h;
      p = dpp_row_sum16(p);
      if ((L & 15) == 15) vr[bn][0][0][L >> 4] = p;
    }
    __syncthreads();   // barrier A

    const int C0 = (nsh[0] + Kc - 1) >> 5, C1 = (nsh[1] + Kc - 1) >> 5;
    const int CM = C0 > C1 ? C0 : C1;
    const int Cb = bn ? C1 : C0;
    float* ydb = &yd[bn][0];
    for (int c = 0; c < CM + 3; ++c) {
      if (c >= 2 && c - 2 < Cb) {
        const int cm = c - 2;
        const float* hsrc = &h2r[bn][cm & 1][0][0];
        for (int k = 0; k < Kc; ++k) {
          v2f hb[8];
          ld16(&hsrc[k * DBn + koff], hb);
          float mh = dppx8_add(dot8(m1c, hb));
          float v = fmaxf(mh + mb1e, 0.0f) * mW2h;
          v = dpp_row_sum16(v);                 // pure-VALU 16-lane reduce
          if ((L & 15) == 15) vr[bn][cm & 1][k][L >> 4] = v;
        }
      }
      if (c >= 3) {
        const int cd = c - 3;                   // drain y for chunk cd
        if (cd < Cb && L < Kc) {
          float4 p = *(const float4*)&vr[bn][cd & 1][L][0];
          ydb[cd * Kc + L] = ((p.x + p.y) + (p.z + p.w)) + mb2v;
        }
      }
      __syncthreads();
    }
  }

  // ======================= joint epilogue =======================
  const int band = tid >> 8;                   // 0..1 (4 waves each)
  const int ct   = tid & 255;
  const int nf   = nsh[band];
  const float mb2e = mb2[band];
  float ylast;
  if (nf > 0) {
    ylast = yd[band][nf - 1];
  } else {
    float4 p = *(const float4*)&vr[band][0][0][0];
    ylast = ((p.x + p.y) + (p.z + p.w)) + mb2e;
  }
  for (int t = nf + ct; t < Tn; t += 256) yd[band][t] = ylast;
  __syncthreads();

  float* orow = out + (band * Bn + b) * Tn;
  #pragma unroll 2
  for (int q = ct; q < Tn / 4; q += 256)
    ((float4*)orow)[q] = ((const float4*)&yd[band][0])[q];
}

extern "C" void kernel_launch(void* const* d_in, const int* in_sizes, int n_in,
                              void* d_out, int out_size, void* d_ws, size_t ws_size,
                              hipStream_t stream) {
  const int*   band_ids = (const int*)  d_in[0];
  const float* dtime    = (const float*)d_in[1];
  const float* z_last   = (const float*)d_in[2];
  const float* projW    = (const float*)d_in[3];
  const float* projB    = (const float*)d_in[4];
  const float* Wih      = (const float*)d_in[5];
  const float* Whh      = (const float*)d_in[6];
  const float* bihp     = (const float*)d_in[7];
  const float* bhhp     = (const float*)d_in[8];
  const float* mW1      = (const float*)d_in[9];
  const float* mb1      = (const float*)d_in[10];
  const float* mW2      = (const float*)d_in[11];
  const float* mb2      = (const float*)d_in[12];
  float* out = (float*)d_out;
  rnn_decoder<<<dim3(Bn), dim3(512), 0, stream>>>(
      band_ids, dtime, z_last, projW, projB, Wih, Whh, bihp, bhhp,
      mW1, mb1, mW2, mb2, out);
}